// Round 6
// baseline (1793.188 us; speedup 1.0000x reference)
//
#include <hip/hip_runtime.h>

typedef __attribute__((ext_vector_type(8))) short bf16x8;
typedef __attribute__((ext_vector_type(4))) float f32x4;

#define DD 512
#define BM 16
#define WW 6
#define NH 8
#define SCS2 40   // per-wave scratch stride (16 rows x 32+8 cols)

__device__ __forceinline__ unsigned short f2bf(float f) {
  unsigned u = __float_as_uint(f);
  u += 0x7fffu + ((u >> 16) & 1u);   // RNE
  return (unsigned short)(u >> 16);
}
__device__ __forceinline__ float bflo(unsigned v) { return __uint_as_float(v << 16); }
__device__ __forceinline__ float bfhi(unsigned v) { return __uint_as_float(v & 0xffff0000u); }
__device__ __forceinline__ int msk8(int row) { return (row ^ (row >> 3)) & 7; }
__device__ __forceinline__ int evsw(int row, int col) { return col ^ (msk8(row) << 3); }

// ---------- prep: transpose float[R][C] -> bf16[C][R] ----------
__global__ void k_tr_bf16(const float* __restrict__ src, unsigned short* __restrict__ dst,
                          int R, int C) {
  __shared__ float tile[64][65];
  int tpc = C >> 6;
  int tr = (blockIdx.x / tpc) << 6;
  int tc = (blockIdx.x % tpc) << 6;
  int t = threadIdx.x;
  #pragma unroll
  for (int i = 0; i < 16; ++i) {
    int idx = i * 256 + t; int r = idx >> 6, c = idx & 63;
    tile[r][c] = src[(size_t)(tr + r) * C + tc + c];
  }
  __syncthreads();
  #pragma unroll
  for (int i = 0; i < 16; ++i) {
    int idx = i * 256 + t; int c = idx >> 6, r = idx & 63;
    dst[(size_t)(tc + c) * R + tr + r] = f2bf(tile[r][c]);
  }
}

// ---------- prep: plain convert float -> bf16 ----------
__global__ void k_cvt4(const float* __restrict__ src, unsigned short* __restrict__ dst, int n4) {
  int i = blockIdx.x * blockDim.x + threadIdx.x;
  if (i < n4) {
    float4 v = ((const float4*)src)[i];
    ushort4 o; o.x = f2bf(v.x); o.y = f2bf(v.y); o.z = f2bf(v.z); o.w = f2bf(v.w);
    ((ushort4*)dst)[i] = o;
  }
}

// ---------- main fused kernel: 16 entities/block, 8 waves = 8 heads, evo in 2 halves ----------
// launch_bounds 2nd arg = min BLOCKS/CU (CUDA semantics, r3 evidence). 2 blocks/CU -> 128 VGPR cap.
// r5 lesson: NO register array may live across a staging burst (qkf[16] spill -> 1.15GB traffic).
__global__ __launch_bounds__(512, 2) void trust_main(
    const float* __restrict__ h_i, const float* __restrict__ evo,
    const float* __restrict__ var_i, const float* __restrict__ var_j,
    const float* __restrict__ bq, const float* __restrict__ bk, const float* __restrict__ bv,
    const float* __restrict__ ld, const float* __restrict__ b1,
    const float* __restrict__ W2, const float* __restrict__ b2,
    const unsigned short* __restrict__ wqT, const unsigned short* __restrict__ wkB,
    const unsigned short* __restrict__ wvT, const unsigned short* __restrict__ w1T,
    float* __restrict__ out) {
  __shared__ unsigned short evo_s[48 * 512];      // 49152 B, one half (8 ents x 6 w), swizzled
  __shared__ unsigned short qh_s[16 * 512];       // 16384 B, h -> Q -> pooled, swizzled
  __shared__ unsigned short scr_s[NH * 16 * SCS2];// 10240 B, per-wave Qk A-frag staging
  __shared__ float score_s[NH * BM * WW];         // 3072 B, scores then attn
  __shared__ float logit_s[BM * NH];              // 512 B
  __shared__ float conf_s[BM];                    // 64 B
  // total 79424 B -> 2 blocks/CU

  const int t = threadIdx.x;
  const int wv = t >> 6;       // wave == head
  const int l = t & 63;
  const int l16 = l & 15;
  const int lq = l >> 4;
  const int e0 = blockIdx.x * BM;

  unsigned short* my = scr_s + wv * (16 * SCS2);

  // decay bias (all lanes, once)
  float biasw[WW];
  {
    float rd = expf(ld[0]);
    float dsum = 0.f;
    #pragma unroll
    for (int w6 = 0; w6 < WW; ++w6) { biasw[w6] = expf(rd * (float)w6); dsum += biasw[w6]; }
    float dinv = 1.f / dsum;
    #pragma unroll
    for (int w6 = 0; w6 < WW; ++w6) biasw[w6] *= dinv;
  }

  const float4* ev4 = (const float4*)evo + (size_t)e0 * (WW * DD / 4);

  // ---- P0: stage evo half0 + h to LDS (bf16, swizzled); conf reduction ----
  {
    #pragma unroll
    for (int i = 0; i < 12; ++i) {
      int idx = i * 512 + t;
      int row = idx >> 7, c4 = idx & 127;
      float4 v = ev4[idx];
      ushort4 o; o.x = f2bf(v.x); o.y = f2bf(v.y); o.z = f2bf(v.z); o.w = f2bf(v.w);
      *(ushort4*)&evo_s[row * 512 + evsw(row, c4 * 4)] = o;
    }
    const float4* h4 = (const float4*)h_i + (size_t)e0 * (DD / 4);
    #pragma unroll
    for (int i = 0; i < 4; ++i) {
      int idx = i * 512 + t;
      int row = idx >> 7, c4 = idx & 127;
      float4 v = h4[idx];
      ushort4 o; o.x = f2bf(v.x); o.y = f2bf(v.y); o.z = f2bf(v.z); o.w = f2bf(v.w);
      *(ushort4*)&qh_s[row * 512 + evsw(row, c4 * 4)] = o;
    }
    int ce = t >> 5, cs = t & 31;
    const float4* vi4 = (const float4*)var_i + (size_t)(e0 + ce) * (DD / 4);
    const float4* vj4 = (const float4*)var_j + (size_t)(e0 + ce) * (DD / 4);
    float si = 0.f, sj = 0.f;
    #pragma unroll
    for (int i = 0; i < 4; ++i) {
      float4 a = vi4[i * 32 + cs]; si += a.x + a.y + a.z + a.w;
      float4 b = vj4[i * 32 + cs]; sj += b.x + b.y + b.z + b.w;
    }
    #pragma unroll
    for (int m = 1; m <= 16; m <<= 1) { si += __shfl_xor(si, m); sj += __shfl_xor(sj, m); }
    if (cs == 0) {
      float ci = 1.f / (1.f + fmaxf(sqrtf(si * (1.f / DD)), 1e-6f));
      float cj = 1.f / (1.f + fmaxf(sqrtf(sj * (1.f / DD)), 1e-6f));
      conf_s[ce] = fmaxf(0.5f * (logf(ci) + logf(cj)), -5.0f);
    }
  }
  __syncthreads();   // B1

  // ---- P1: Q = h @ Wq + bq (wave -> its head's 64 cols); fold qb = Q.bk ----
  float qb_r[4];
  {
    f32x4 qacc[4] = {};
    const unsigned short* wqp = wqT + (size_t)(wv * 64 + l16) * DD + lq * 8;
    #pragma unroll
    for (int kst = 0; kst < 16; ++kst) {
      bf16x8 a = *(const bf16x8*)&qh_s[l16 * 512 + evsw(l16, kst * 32 + lq * 8)];
      #pragma unroll
      for (int ct = 0; ct < 4; ++ct) {
        bf16x8 b = *(const bf16x8*)&wqp[ct * 16 * DD + kst * 32];
        qacc[ct] = __builtin_amdgcn_mfma_f32_16x16x32_bf16(a, b, qacc[ct], 0, 0, 0);
      }
    }
    __syncthreads();   // B2: all waves done reading h before Q overwrites qh_s
    #pragma unroll
    for (int r = 0; r < 4; ++r) qb_r[r] = 0.f;
    #pragma unroll
    for (int ct = 0; ct < 4; ++ct) {
      int col = wv * 64 + ct * 16 + l16;
      float bqv = bq[col], bkv = bk[col];
      #pragma unroll
      for (int r = 0; r < 4; ++r) {
        float qv = qacc[ct][r] + bqv;
        qb_r[r] += qv * bkv;
        int row = lq * 4 + r;
        qh_s[row * 512 + evsw(row, col)] = f2bf(qv);
      }
    }
    #pragma unroll
    for (int r = 0; r < 4; ++r) {
      #pragma unroll
      for (int m = 1; m <= 8; m <<= 1) qb_r[r] += __shfl_xor(qb_r[r], m);
    }
  }
  // (no barrier: the score loop reads only this wave's own Q cols; same-wave LDS is ordered)

  f32x4 pacc[4] = {};   // pooled accumulator (both halves)
  const unsigned short* wvp = wvT + (size_t)(wv * 64 + l16) * DD + lq * 8;
  const unsigned short* wkp = wkB + (size_t)l16 * DD + wv * 64 + lq * 8;

  #pragma unroll
  for (int H = 0; H < 2; ++H) {
    if (H == 1) {
      __syncthreads();   // B3: all waves done reading evo half0
      const float4* ev4b = ev4 + 48 * 128;
      #pragma unroll
      for (int i = 0; i < 12; ++i) {
        int idx = i * 512 + t;
        int row = idx >> 7, c4 = idx & 127;
        float4 v = ev4b[idx];
        ushort4 o; o.x = f2bf(v.x); o.y = f2bf(v.y); o.z = f2bf(v.z); o.w = f2bf(v.w);
        *(ushort4*)&evo_s[row * 512 + evsw(row, c4 * 4)] = o;
      }
      __syncthreads();   // B4
    }

    // ---- S = Qk @ evo_half^T; Qk produced chunk-by-chunk, consumed immediately ----
    f32x4 sacc[3] = {};
    #pragma unroll
    for (int ch = 0; ch < 16; ++ch) {
      f32x4 qk0 = {}, qk1 = {};
      #pragma unroll
      for (int kst = 0; kst < 2; ++kst) {
        bf16x8 a = *(const bf16x8*)&qh_s[l16 * 512 + evsw(l16, wv * 64 + kst * 32 + lq * 8)];
        bf16x8 b0 = *(const bf16x8*)&wkp[(size_t)(ch * 32) * DD + kst * 32];
        bf16x8 b1 = *(const bf16x8*)&wkp[(size_t)(ch * 32 + 16) * DD + kst * 32];
        qk0 = __builtin_amdgcn_mfma_f32_16x16x32_bf16(a, b0, qk0, 0, 0, 0);
        qk1 = __builtin_amdgcn_mfma_f32_16x16x32_bf16(a, b1, qk1, 0, 0, 0);
      }
      #pragma unroll
      for (int r = 0; r < 4; ++r) {
        my[(lq * 4 + r) * SCS2 + l16]      = f2bf(qk0[r]);
        my[(lq * 4 + r) * SCS2 + 16 + l16] = f2bf(qk1[r]);
      }
      bf16x8 afr = *(const bf16x8*)&my[l16 * SCS2 + lq * 8];   // A-frag Qk[l16][ch*32+lq*8+j]
      #pragma unroll
      for (int n6 = 0; n6 < 3; ++n6) {
        int L = n6 * 16 + l16;
        bf16x8 b = *(const bf16x8*)&evo_s[L * 512 + ((ch * 32 + lq * 8) ^ (msk8(L) << 3))];
        sacc[n6] = __builtin_amdgcn_mfma_f32_16x16x32_bf16(afr, b, sacc[n6], 0, 0, 0);
      }
    }
    // extract S[e][w] (global evo row = 48H + L; useful iff w in [0,6))
    #pragma unroll
    for (int n6 = 0; n6 < 3; ++n6) {
      #pragma unroll
      for (int r = 0; r < 4; ++r) {
        int e = lq * 4 + r;
        int w = 48 * H + n6 * 16 + l16 - 6 * e;
        if (w >= 0 && w < WW)
          score_s[wv * 96 + e * 6 + w] = sacc[n6][r];
      }
    }
    // softmax for this half's entities (attn written back by l16==0 lanes)
    #pragma unroll
    for (int r = 0; r < 4; ++r) {
      int e = lq * 4 + r, eL = e - 8 * H;
      if (eL >= 0 && eL < 8) {
        float sc[WW]; float mx = -1e30f;
        #pragma unroll
        for (int w6 = 0; w6 < WW; ++w6) {
          sc[w6] = 0.125f * (score_s[wv * 96 + e * 6 + w6] + qb_r[r]) + biasw[w6];
          mx = fmaxf(mx, sc[w6]);
        }
        float ssum = 0.f;
        #pragma unroll
        for (int w6 = 0; w6 < WW; ++w6) { sc[w6] = expf(sc[w6] - mx); ssum += sc[w6]; }
        float sinv = 1.f / ssum;
        if (l16 == 0) {
          #pragma unroll
          for (int w6 = 0; w6 < WW; ++w6) score_s[wv * 96 + e * 6 + w6] = sc[w6] * sinv;
        }
      }
    }

    // ---- agg (lane = entity l16, cols lq*8+j) -> pooled MFMA A-frag direct ----
    float aw6[WW];
    {
      bool inh = ((l16 >> 3) == H);
      #pragma unroll
      for (int w6 = 0; w6 < WW; ++w6) {
        float v = score_s[wv * 96 + l16 * 6 + w6];
        aw6[w6] = inh ? v : 0.f;    // out-of-half lanes contribute exact zeros
      }
    }
    #pragma unroll
    for (int ch = 0; ch < 16; ++ch) {
      float a0 = 0.f, a1 = 0.f, a2 = 0.f, a3 = 0.f, a4 = 0.f, a5 = 0.f, a6 = 0.f, a7 = 0.f;
      #pragma unroll
      for (int w6 = 0; w6 < WW; ++w6) {
        int L = (l16 & 7) * 6 + w6;
        uint4 vv = *(const uint4*)&evo_s[L * 512 + ((ch * 32 + lq * 8) ^ (msk8(L) << 3))];
        float aww = aw6[w6];
        a0 += aww * bflo(vv.x); a1 += aww * bfhi(vv.x);
        a2 += aww * bflo(vv.y); a3 += aww * bfhi(vv.y);
        a4 += aww * bflo(vv.z); a5 += aww * bfhi(vv.z);
        a6 += aww * bflo(vv.w); a7 += aww * bfhi(vv.w);
      }
      bf16x8 af;
      af[0] = (short)f2bf(a0); af[1] = (short)f2bf(a1);
      af[2] = (short)f2bf(a2); af[3] = (short)f2bf(a3);
      af[4] = (short)f2bf(a4); af[5] = (short)f2bf(a5);
      af[6] = (short)f2bf(a6); af[7] = (short)f2bf(a7);
      #pragma unroll
      for (int ct = 0; ct < 4; ++ct) {
        bf16x8 b = *(const bf16x8*)&wvp[(size_t)(ct * 16) * DD + ch * 32];
        pacc[ct] = __builtin_amdgcn_mfma_f32_16x16x32_bf16(af, b, pacc[ct], 0, 0, 0);
      }
    }
  }

  // pooled -> qh_s (bf16, swizzled); each wave writes only its own head's cols
  #pragma unroll
  for (int ct = 0; ct < 4; ++ct) {
    int col = wv * 64 + ct * 16 + l16;
    float bvv = bv[col];
    #pragma unroll
    for (int r = 0; r < 4; ++r) {
      int row = lq * 4 + r;
      qh_s[row * 512 + evsw(row, col)] = f2bf(pacc[ct][r] + bvv);
    }
  }
  __syncthreads();   // B5

  // ---- P6: hmid = gelu(pooled @ W1 + b1); logit partials ----
  {
    f32x4 hacc[2] = {};
    const unsigned short* w1p = w1T + (size_t)(wv * 32 + l16) * DD + lq * 8;
    #pragma unroll
    for (int kst = 0; kst < 16; ++kst) {
      bf16x8 a = *(const bf16x8*)&qh_s[l16 * 512 + evsw(l16, kst * 32 + lq * 8)];
      #pragma unroll
      for (int ct = 0; ct < 2; ++ct) {
        bf16x8 b = *(const bf16x8*)&w1p[(size_t)(ct * 16) * DD + kst * 32];
        hacc[ct] = __builtin_amdgcn_mfma_f32_16x16x32_bf16(a, b, hacc[ct], 0, 0, 0);
      }
    }
    float lg[4] = {0.f, 0.f, 0.f, 0.f};
    #pragma unroll
    for (int ct = 0; ct < 2; ++ct) {
      int m = wv * 32 + ct * 16 + l16;
      float b1v = b1[m], w2v = W2[m];
      #pragma unroll
      for (int r = 0; r < 4; ++r) {
        float x = hacc[ct][r] + b1v;
        float g = 0.5f * x * (1.f + erff(x * 0.70710678118f));
        lg[r] += g * w2v;
      }
    }
    #pragma unroll
    for (int r = 0; r < 4; ++r) {
      #pragma unroll
      for (int m = 1; m <= 8; m <<= 1) lg[r] += __shfl_xor(lg[r], m);
    }
    if (l16 == 0) {
      #pragma unroll
      for (int r = 0; r < 4; ++r) logit_s[(lq * 4 + r) * NH + wv] = lg[r];
    }
  }
  __syncthreads();   // B6

  // ---- P7: combine + sigmoid ----
  if (t < BM) {
    float s = 0.f;
    #pragma unroll
    for (int w8 = 0; w8 < NH; ++w8) s += logit_s[t * NH + w8];
    s += b2[0] + conf_s[t];
    out[e0 + t] = 1.f / (1.f + expf(-s));
  }
}

extern "C" void kernel_launch(void* const* d_in, const int* in_sizes, int n_in,
                              void* d_out, int out_size, void* d_ws, size_t ws_size,
                              hipStream_t stream) {
  (void)in_sizes; (void)n_in; (void)out_size; (void)ws_size;
  const float* h_i = (const float*)d_in[0];
  const float* evo = (const float*)d_in[1];
  const float* vi  = (const float*)d_in[2];
  const float* vj  = (const float*)d_in[3];
  const float* Wq  = (const float*)d_in[4];
  const float* bq  = (const float*)d_in[5];
  const float* Wk  = (const float*)d_in[6];
  const float* bk  = (const float*)d_in[7];
  const float* Wv  = (const float*)d_in[8];
  const float* bv  = (const float*)d_in[9];
  const float* ld  = (const float*)d_in[10];
  const float* W1  = (const float*)d_in[11];
  const float* b1  = (const float*)d_in[12];
  const float* W2  = (const float*)d_in[13];
  const float* b2  = (const float*)d_in[14];
  float* out = (float*)d_out;

  unsigned short* ws  = (unsigned short*)d_ws;
  unsigned short* wqT = ws;            // [512][512] bf16, WqT[n][k]=Wq[k][n]
  unsigned short* wkB = ws + 262144;   // [512][512] bf16, plain Wk
  unsigned short* wvT = ws + 524288;   // [512][512] bf16, WvT[n][k]=Wv[k][n]
  unsigned short* w1T = ws + 786432;   // [256][512] bf16, W1T[m][k]=W1[k][m]

  k_tr_bf16<<<64, 256, 0, stream>>>(Wq, wqT, 512, 512);
  k_cvt4<<<256, 256, 0, stream>>>(Wk, wkB, 65536);
  k_tr_bf16<<<64, 256, 0, stream>>>(Wv, wvT, 512, 512);
  k_tr_bf16<<<32, 256, 0, stream>>>(W1, w1T, 512, 256);
  trust_main<<<3125, 512, 0, stream>>>(h_i, evo, vi, vj, bq, bk, bv, ld, b1, W2, b2,
                                       wqT, wkB, wvT, w1T, out);
}

// Round 7
// 1352.645 us; speedup vs baseline: 1.3257x; 1.3257x over previous
//
#include <hip/hip_runtime.h>

typedef __attribute__((ext_vector_type(8))) short bf16x8;
typedef __attribute__((ext_vector_type(4))) float f32x4;

#define DD 512
#define BM 8      // entities per block
#define WW 6
#define NH 8
#define SCS2 40   // per-wave scratch stride (16 rows x 32+8 cols, u16)

__device__ __forceinline__ unsigned short f2bf(float f) {
  unsigned u = __float_as_uint(f);
  u += 0x7fffu + ((u >> 16) & 1u);   // RNE
  return (unsigned short)(u >> 16);
}
__device__ __forceinline__ float bflo(unsigned v) { return __uint_as_float(v << 16); }
__device__ __forceinline__ float bfhi(unsigned v) { return __uint_as_float(v & 0xffff0000u); }
__device__ __forceinline__ int msk8(int row) { return (row ^ (row >> 3)) & 7; }
__device__ __forceinline__ int evsw(int row, int col) { return col ^ (msk8(row) << 3); }
#define SCHED_FENCE() __builtin_amdgcn_sched_barrier(0)

// ---------- prep: transpose float[R][C] -> bf16[C][R] ----------
__global__ void k_tr_bf16(const float* __restrict__ src, unsigned short* __restrict__ dst,
                          int R, int C) {
  __shared__ float tile[64][65];
  int tpc = C >> 6;
  int tr = (blockIdx.x / tpc) << 6;
  int tc = (blockIdx.x % tpc) << 6;
  int t = threadIdx.x;
  #pragma unroll
  for (int i = 0; i < 16; ++i) {
    int idx = i * 256 + t; int r = idx >> 6, c = idx & 63;
    tile[r][c] = src[(size_t)(tr + r) * C + tc + c];
  }
  __syncthreads();
  #pragma unroll
  for (int i = 0; i < 16; ++i) {
    int idx = i * 256 + t; int c = idx >> 6, r = idx & 63;
    dst[(size_t)(tc + c) * R + tr + r] = f2bf(tile[r][c]);
  }
}

// ---------- prep: plain convert float -> bf16 ----------
__global__ void k_cvt4(const float* __restrict__ src, unsigned short* __restrict__ dst, int n4) {
  int i = blockIdx.x * blockDim.x + threadIdx.x;
  if (i < n4) {
    float4 v = ((const float4*)src)[i];
    ushort4 o; o.x = f2bf(v.x); o.y = f2bf(v.y); o.z = f2bf(v.z); o.w = f2bf(v.w);
    ((ushort4*)dst)[i] = o;
  }
}

// ---------- main fused kernel: 8 entities/block, 8 waves = 8 heads, full evo tile ----------
// launch_bounds 2nd arg = min BLOCKS/CU (CUDA semantics, r3 evidence) -> 128 total-reg cap.
// r5/r6 lesson: full unroll of global-load loops => load hoisting => spills under the cap.
//   => unroll 1 on ch-loops, unroll 2/4 on k-loops, sched_barrier(0) at phase seams.
__global__ __launch_bounds__(512, 2) void trust_main(
    const float* __restrict__ h_i, const float* __restrict__ evo,
    const float* __restrict__ var_i, const float* __restrict__ var_j,
    const float* __restrict__ bq, const float* __restrict__ bk, const float* __restrict__ bv,
    const float* __restrict__ ld, const float* __restrict__ b1,
    const float* __restrict__ W2, const float* __restrict__ b2,
    const unsigned short* __restrict__ wqT, const unsigned short* __restrict__ wkB,
    const unsigned short* __restrict__ wvT, const unsigned short* __restrict__ w1T,
    float* __restrict__ out) {
  __shared__ unsigned short evo_s[48 * 512];      // 49152 B, 8 ents x 6 w, swizzled
  __shared__ unsigned short qh_s[16 * 512];       // 16384 B, h -> Q -> pooled (rows 8-15 dummy)
  __shared__ unsigned short scr_s[NH * 16 * SCS2];// 10240 B, per-wave Qk A-frag staging
  __shared__ float score_s[NH * BM * WW];         // 1536 B, scores then attn
  __shared__ float logit_s[16 * NH];              // 512 B (rows 8-15 dummy)
  __shared__ float conf_s[BM];                    // 32 B
  // total 77856 B -> 2 blocks/CU

  const int t = threadIdx.x;
  const int wv = t >> 6;       // wave == head
  const int l = t & 63;
  const int l16 = l & 15;
  const int lq = l >> 4;
  const int e0 = blockIdx.x * BM;

  unsigned short* my = scr_s + wv * (16 * SCS2);

  // decay bias (all lanes, once)
  float biasw[WW];
  {
    float rd = expf(ld[0]);
    float dsum = 0.f;
    #pragma unroll
    for (int w6 = 0; w6 < WW; ++w6) { biasw[w6] = expf(rd * (float)w6); dsum += biasw[w6]; }
    float dinv = 1.f / dsum;
    #pragma unroll
    for (int w6 = 0; w6 < WW; ++w6) biasw[w6] *= dinv;
  }

  // ---- P0: stage evo (full 8-ent tile) + h to LDS (bf16, swizzled); conf ----
  {
    const float4* ev4 = (const float4*)evo + (size_t)e0 * (WW * DD / 4);
    #pragma unroll
    for (int i = 0; i < 12; ++i) {
      int idx = i * 512 + t;
      int row = idx >> 7, c4 = idx & 127;
      float4 v = ev4[idx];
      ushort4 o; o.x = f2bf(v.x); o.y = f2bf(v.y); o.z = f2bf(v.z); o.w = f2bf(v.w);
      *(ushort4*)&evo_s[row * 512 + evsw(row, c4 * 4)] = o;
    }
    const float4* h4 = (const float4*)h_i + (size_t)e0 * (DD / 4);
    #pragma unroll
    for (int i = 0; i < 2; ++i) {
      int idx = i * 512 + t;
      int row = idx >> 7, c4 = idx & 127;
      float4 v = h4[idx];
      ushort4 o; o.x = f2bf(v.x); o.y = f2bf(v.y); o.z = f2bf(v.z); o.w = f2bf(v.w);
      *(ushort4*)&qh_s[row * 512 + evsw(row, c4 * 4)] = o;
    }
    // conf: wave wv reduces entity (e0+wv)'s var rows
    const float4* vi4 = (const float4*)var_i + (size_t)(e0 + wv) * (DD / 4);
    const float4* vj4 = (const float4*)var_j + (size_t)(e0 + wv) * (DD / 4);
    float si = 0.f, sj = 0.f;
    #pragma unroll
    for (int i = 0; i < 2; ++i) {
      float4 a = vi4[l * 2 + i]; si += a.x + a.y + a.z + a.w;
      float4 b = vj4[l * 2 + i]; sj += b.x + b.y + b.z + b.w;
    }
    #pragma unroll
    for (int m = 1; m <= 32; m <<= 1) { si += __shfl_xor(si, m); sj += __shfl_xor(sj, m); }
    if (l == 0) {
      float ci = 1.f / (1.f + fmaxf(sqrtf(si * (1.f / DD)), 1e-6f));
      float cj = 1.f / (1.f + fmaxf(sqrtf(sj * (1.f / DD)), 1e-6f));
      conf_s[wv] = fmaxf(0.5f * (logf(ci) + logf(cj)), -5.0f);
    }
  }
  __syncthreads();   // B1
  SCHED_FENCE();

  // ---- P1: Q = h @ Wq + bq (wave -> its head's 64 cols); fold qb = Q.bk ----
  float qb_r[4];
  {
    f32x4 qacc[4] = {};
    const unsigned short* wqp = wqT + (size_t)(wv * 64 + l16) * DD + lq * 8;
    #pragma unroll 2
    for (int kst = 0; kst < 16; ++kst) {
      bf16x8 a = *(const bf16x8*)&qh_s[l16 * 512 + evsw(l16, kst * 32 + lq * 8)];
      #pragma unroll
      for (int ct = 0; ct < 4; ++ct) {
        bf16x8 b = *(const bf16x8*)&wqp[ct * 16 * DD + kst * 32];
        qacc[ct] = __builtin_amdgcn_mfma_f32_16x16x32_bf16(a, b, qacc[ct], 0, 0, 0);
      }
    }
    __syncthreads();   // B2: all waves done reading h before Q overwrites qh_s
    #pragma unroll
    for (int r = 0; r < 4; ++r) qb_r[r] = 0.f;
    #pragma unroll
    for (int ct = 0; ct < 4; ++ct) {
      int col = wv * 64 + ct * 16 + l16;
      float bqv = bq[col], bkv = bk[col];
      #pragma unroll
      for (int r = 0; r < 4; ++r) {
        float qv = qacc[ct][r] + bqv;
        qb_r[r] += qv * bkv;
        int row = lq * 4 + r;
        qh_s[row * 512 + evsw(row, col)] = f2bf(qv);
      }
    }
    #pragma unroll
    for (int r = 0; r < 4; ++r) {
      #pragma unroll
      for (int m = 1; m <= 8; m <<= 1) qb_r[r] += __shfl_xor(qb_r[r], m);
    }
  }
  SCHED_FENCE();
  // (no barrier: score loop reads only this wave's own Q cols; same-wave LDS is ordered)

  // ---- score phase: Qk chunk (2+... MFMAs) -> stage -> A-frag -> 3 score MFMAs ----
  f32x4 sacc0 = {}, sacc1 = {}, sacc2 = {};
  {
    const unsigned short* wkp = wkB + (size_t)l16 * DD + wv * 64 + lq * 8;
    #pragma unroll 1
    for (int ch = 0; ch < 16; ++ch) {
      f32x4 qk0 = {}, qk1 = {};
      #pragma unroll
      for (int kst = 0; kst < 2; ++kst) {
        bf16x8 a = *(const bf16x8*)&qh_s[l16 * 512 + evsw(l16, wv * 64 + kst * 32 + lq * 8)];
        bf16x8 b0 = *(const bf16x8*)&wkp[(size_t)(ch * 32) * DD + kst * 32];
        bf16x8 b1 = *(const bf16x8*)&wkp[(size_t)(ch * 32 + 16) * DD + kst * 32];
        qk0 = __builtin_amdgcn_mfma_f32_16x16x32_bf16(a, b0, qk0, 0, 0, 0);
        qk1 = __builtin_amdgcn_mfma_f32_16x16x32_bf16(a, b1, qk1, 0, 0, 0);
      }
      #pragma unroll
      for (int r = 0; r < 4; ++r) {
        my[(lq * 4 + r) * SCS2 + l16]      = f2bf(qk0[r]);
        my[(lq * 4 + r) * SCS2 + 16 + l16] = f2bf(qk1[r]);
      }
      bf16x8 afr = *(const bf16x8*)&my[l16 * SCS2 + lq * 8];
      {
        int L0 = l16;
        bf16x8 b = *(const bf16x8*)&evo_s[L0 * 512 + ((ch * 32 + lq * 8) ^ (msk8(L0) << 3))];
        sacc0 = __builtin_amdgcn_mfma_f32_16x16x32_bf16(afr, b, sacc0, 0, 0, 0);
      }
      {
        int L1 = 16 + l16;
        bf16x8 b = *(const bf16x8*)&evo_s[L1 * 512 + ((ch * 32 + lq * 8) ^ (msk8(L1) << 3))];
        sacc1 = __builtin_amdgcn_mfma_f32_16x16x32_bf16(afr, b, sacc1, 0, 0, 0);
      }
      {
        int L2 = 32 + l16;
        bf16x8 b = *(const bf16x8*)&evo_s[L2 * 512 + ((ch * 32 + lq * 8) ^ (msk8(L2) << 3))];
        sacc2 = __builtin_amdgcn_mfma_f32_16x16x32_bf16(afr, b, sacc2, 0, 0, 0);
      }
    }
  }
  SCHED_FENCE();

  // extract S[e][w] (L = 6e+w <= 47 => e <= 7 automatically)
  #pragma unroll
  for (int r = 0; r < 4; ++r) {
    int e = lq * 4 + r;
    {
      int w = l16 - 6 * e;
      if (w >= 0 && w < WW) score_s[wv * 48 + e * 6 + w] = sacc0[r];
    }
    {
      int w = 16 + l16 - 6 * e;
      if (w >= 0 && w < WW) score_s[wv * 48 + e * 6 + w] = sacc1[r];
    }
    {
      int w = 32 + l16 - 6 * e;
      if (w >= 0 && w < WW) score_s[wv * 48 + e * 6 + w] = sacc2[r];
    }
  }
  // softmax (per-wave slice; attn written back by l16==0 lanes)
  #pragma unroll
  for (int r = 0; r < 4; ++r) {
    int e = lq * 4 + r;
    if (e < BM) {
      float sc[WW]; float mx = -1e30f;
      #pragma unroll
      for (int w6 = 0; w6 < WW; ++w6) {
        sc[w6] = 0.125f * (score_s[wv * 48 + e * 6 + w6] + qb_r[r]) + biasw[w6];
        mx = fmaxf(mx, sc[w6]);
      }
      float ssum = 0.f;
      #pragma unroll
      for (int w6 = 0; w6 < WW; ++w6) { sc[w6] = expf(sc[w6] - mx); ssum += sc[w6]; }
      float sinv = 1.f / ssum;
      if (l16 == 0) {
        #pragma unroll
        for (int w6 = 0; w6 < WW; ++w6) score_s[wv * 48 + e * 6 + w6] = sc[w6] * sinv;
      }
    }
  }
  SCHED_FENCE();

  // ---- agg (lane = entity l16<8, cols lq*8+j) -> pooled MFMA A-frag direct ----
  f32x4 pacc[4] = {};
  {
    float aw6[WW];
    #pragma unroll
    for (int w6 = 0; w6 < WW; ++w6) {
      float v = score_s[wv * 48 + (l16 & 7) * 6 + w6];
      aw6[w6] = (l16 < BM) ? v : 0.f;   // lanes 8-15 contribute exact zeros
    }
    const unsigned short* wvp = wvT + (size_t)(wv * 64 + l16) * DD + lq * 8;
    #pragma unroll 1
    for (int ch = 0; ch < 16; ++ch) {
      float a0 = 0.f, a1 = 0.f, a2 = 0.f, a3 = 0.f, a4 = 0.f, a5 = 0.f, a6 = 0.f, a7 = 0.f;
      #pragma unroll
      for (int w6 = 0; w6 < WW; ++w6) {
        int L = (l16 & 7) * 6 + w6;
        uint4 vv = *(const uint4*)&evo_s[L * 512 + ((ch * 32 + lq * 8) ^ (msk8(L) << 3))];
        float aww = aw6[w6];
        a0 += aww * bflo(vv.x); a1 += aww * bfhi(vv.x);
        a2 += aww * bflo(vv.y); a3 += aww * bfhi(vv.y);
        a4 += aww * bflo(vv.z); a5 += aww * bfhi(vv.z);
        a6 += aww * bflo(vv.w); a7 += aww * bfhi(vv.w);
      }
      bf16x8 af;
      af[0] = (short)f2bf(a0); af[1] = (short)f2bf(a1);
      af[2] = (short)f2bf(a2); af[3] = (short)f2bf(a3);
      af[4] = (short)f2bf(a4); af[5] = (short)f2bf(a5);
      af[6] = (short)f2bf(a6); af[7] = (short)f2bf(a7);
      #pragma unroll
      for (int ct = 0; ct < 4; ++ct) {
        bf16x8 b = *(const bf16x8*)&wvp[(size_t)(ct * 16) * DD + ch * 32];
        pacc[ct] = __builtin_amdgcn_mfma_f32_16x16x32_bf16(af, b, pacc[ct], 0, 0, 0);
      }
    }
  }
  SCHED_FENCE();

  // pooled -> qh_s (bf16, swizzled); rows 8-15 are exact 0 + bv (harmless)
  #pragma unroll
  for (int ct = 0; ct < 4; ++ct) {
    int col = wv * 64 + ct * 16 + l16;
    float bvv = bv[col];
    #pragma unroll
    for (int r = 0; r < 4; ++r) {
      int row = lq * 4 + r;
      qh_s[row * 512 + evsw(row, col)] = f2bf(pacc[ct][r] + bvv);
    }
  }
  __syncthreads();   // B3

  // ---- P6: hmid = gelu(pooled @ W1 + b1); logit partials ----
  {
    f32x4 hacc[2] = {};
    const unsigned short* w1p = w1T + (size_t)(wv * 32 + l16) * DD + lq * 8;
    #pragma unroll 4
    for (int kst = 0; kst < 16; ++kst) {
      bf16x8 a = *(const bf16x8*)&qh_s[l16 * 512 + evsw(l16, kst * 32 + lq * 8)];
      #pragma unroll
      for (int ct = 0; ct < 2; ++ct) {
        bf16x8 b = *(const bf16x8*)&w1p[(size_t)(ct * 16) * DD + kst * 32];
        hacc[ct] = __builtin_amdgcn_mfma_f32_16x16x32_bf16(a, b, hacc[ct], 0, 0, 0);
      }
    }
    float lg[4] = {0.f, 0.f, 0.f, 0.f};
    #pragma unroll
    for (int ct = 0; ct < 2; ++ct) {
      int m = wv * 32 + ct * 16 + l16;
      float b1v = b1[m], w2v = W2[m];
      #pragma unroll
      for (int r = 0; r < 4; ++r) {
        float x = hacc[ct][r] + b1v;
        float g = 0.5f * x * (1.f + erff(x * 0.70710678118f));
        lg[r] += g * w2v;
      }
    }
    #pragma unroll
    for (int r = 0; r < 4; ++r) {
      #pragma unroll
      for (int m = 1; m <= 8; m <<= 1) lg[r] += __shfl_xor(lg[r], m);
    }
    if (l16 == 0) {
      #pragma unroll
      for (int r = 0; r < 4; ++r) logit_s[(lq * 4 + r) * NH + wv] = lg[r];
    }
  }
  __syncthreads();   // B4

  // ---- P7: combine + sigmoid ----
  if (t < BM) {
    float s = 0.f;
    #pragma unroll
    for (int w8 = 0; w8 < NH; ++w8) s += logit_s[t * NH + w8];
    s += b2[0] + conf_s[t];
    out[e0 + t] = 1.f / (1.f + expf(-s));
  }
}

extern "C" void kernel_launch(void* const* d_in, const int* in_sizes, int n_in,
                              void* d_out, int out_size, void* d_ws, size_t ws_size,
                              hipStream_t stream) {
  (void)in_sizes; (void)n_in; (void)out_size; (void)ws_size;
  const float* h_i = (const float*)d_in[0];
  const float* evo = (const float*)d_in[1];
  const float* vi  = (const float*)d_in[2];
  const float* vj  = (const float*)d_in[3];
  const float* Wq  = (const float*)d_in[4];
  const float* bq  = (const float*)d_in[5];
  const float* Wk  = (const float*)d_in[6];
  const float* bk  = (const float*)d_in[7];
  const float* Wv  = (const float*)d_in[8];
  const float* bv  = (const float*)d_in[9];
  const float* ld  = (const float*)d_in[10];
  const float* W1  = (const float*)d_in[11];
  const float* b1  = (const float*)d_in[12];
  const float* W2  = (const float*)d_in[13];
  const float* b2  = (const float*)d_in[14];
  float* out = (float*)d_out;

  unsigned short* ws  = (unsigned short*)d_ws;
  unsigned short* wqT = ws;            // [512][512] bf16, WqT[n][k]=Wq[k][n]
  unsigned short* wkB = ws + 262144;   // [512][512] bf16, plain Wk
  unsigned short* wvT = ws + 524288;   // [512][512] bf16, WvT[n][k]=Wv[k][n]
  unsigned short* w1T = ws + 786432;   // [256][512] bf16, W1T[m][k]=W1[k][m]

  k_tr_bf16<<<64, 256, 0, stream>>>(Wq, wqT, 512, 512);
  k_cvt4<<<256, 256, 0, stream>>>(Wk, wkB, 65536);
  k_tr_bf16<<<64, 256, 0, stream>>>(Wv, wvT, 512, 512);
  k_tr_bf16<<<32, 256, 0, stream>>>(W1, w1T, 512, 256);
  trust_main<<<6250, 512, 0, stream>>>(h_i, evo, vi, vj, bq, bk, bv, ld, b1, W2, b2,
                                       wqT, wkB, wvT, w1T, out);
}